// Round 1
// baseline (1317.167 us; speedup 1.0000x reference)
//
#include <hip/hip_runtime.h>

#define W_DIM   512
#define IN_CH   512
#define OUT_CH  3
#define HW      16384          // 128*128
#define BATCH   32
#define CLAMP_V 256.0f

// gain = 1/sqrt(512) for both fc_gain and weight_gain
#define GAIN 0.04419417382415922f

// ---------------------------------------------------------------------------
// Kernel 1: one wave per (b, i) pair.
//   styles[b][i] = (dot(w[b,:], aw[i,:]) * GAIN + ab[i]) * GAIN
//   m[b][o][i]   = wk[o][i] * styles[b][i]
// Grid: 4096 blocks * 256 threads = 16384 waves = 32 batches * 512 channels.
// ---------------------------------------------------------------------------
__global__ __launch_bounds__(256) void styles_kernel(
    const float* __restrict__ w,    // [32, 512]
    const float* __restrict__ aw,   // [512, 512]
    const float* __restrict__ ab,   // [512]
    const float* __restrict__ wk,   // [3, 512]  (weight[:, :, 0, 0])
    float* __restrict__ m)          // [32, 3, 512] workspace
{
    const int wid  = blockIdx.x * (blockDim.x >> 6) + (threadIdx.x >> 6);
    const int lane = threadIdx.x & 63;
    const int b = wid >> 9;          // / 512
    const int i = wid & 511;         // % 512

    const float* wrow = w  + b * W_DIM;
    const float* arow = aw + i * W_DIM;

    float sum = 0.0f;
    #pragma unroll
    for (int k = lane; k < W_DIM; k += 64)
        sum += wrow[k] * arow[k];

    // full-wave butterfly reduction (wave = 64 on CDNA)
    #pragma unroll
    for (int off = 32; off > 0; off >>= 1)
        sum += __shfl_xor(sum, off, 64);

    const float style = (sum * GAIN + ab[i]) * GAIN;

    if (lane < OUT_CH)
        m[(b * OUT_CH + lane) * IN_CH + i] = wk[lane * IN_CH + i] * style;
}

// ---------------------------------------------------------------------------
// Kernel 2: modulated 1x1 conv, memory-bound streaming of x.
// Grid: 32 batches * 16 blocks, 256 threads; thread owns one float4 (4 px).
// ---------------------------------------------------------------------------
__global__ __launch_bounds__(256) void torgb_kernel(
    const float* __restrict__ x,     // [32, 512, 16384]
    const float* __restrict__ m,     // [32, 3, 512]
    const float* __restrict__ bias,  // [3]
    float* __restrict__ out)         // [32, 3, 16384]
{
    __shared__ float sm[OUT_CH * IN_CH];   // 6 KiB

    const int b   = blockIdx.x >> 4;   // 16 blocks per batch
    const int blk = blockIdx.x & 15;

    // stage this batch's modulated weights into LDS
    for (int t = threadIdx.x; t < OUT_CH * IN_CH; t += 256)
        sm[t] = m[b * OUT_CH * IN_CH + t];
    __syncthreads();

    const int p4 = blk * 256 + threadIdx.x;            // float4 index in plane
    const float4* xb = (const float4*)(x + (size_t)b * IN_CH * HW) + p4;

    float4 a0 = {0.f, 0.f, 0.f, 0.f};
    float4 a1 = {0.f, 0.f, 0.f, 0.f};
    float4 a2 = {0.f, 0.f, 0.f, 0.f};

    #pragma unroll 8
    for (int i = 0; i < IN_CH; ++i) {
        const float4 xv = xb[i * (HW / 4)];            // coalesced dwordx4
        const float m0 = sm[i];                        // broadcast LDS reads
        const float m1 = sm[IN_CH + i];
        const float m2 = sm[2 * IN_CH + i];
        a0.x = fmaf(xv.x, m0, a0.x); a0.y = fmaf(xv.y, m0, a0.y);
        a0.z = fmaf(xv.z, m0, a0.z); a0.w = fmaf(xv.w, m0, a0.w);
        a1.x = fmaf(xv.x, m1, a1.x); a1.y = fmaf(xv.y, m1, a1.y);
        a1.z = fmaf(xv.z, m1, a1.z); a1.w = fmaf(xv.w, m1, a1.w);
        a2.x = fmaf(xv.x, m2, a2.x); a2.y = fmaf(xv.y, m2, a2.y);
        a2.z = fmaf(xv.z, m2, a2.z); a2.w = fmaf(xv.w, m2, a2.w);
    }

    const float b0 = bias[0], b1 = bias[1], b2 = bias[2];

    auto clamp4 = [](float4 v, float bb) {
        float4 r;
        r.x = fminf(fmaxf(v.x + bb, -CLAMP_V), CLAMP_V);
        r.y = fminf(fmaxf(v.y + bb, -CLAMP_V), CLAMP_V);
        r.z = fminf(fmaxf(v.z + bb, -CLAMP_V), CLAMP_V);
        r.w = fminf(fmaxf(v.w + bb, -CLAMP_V), CLAMP_V);
        return r;
    };

    float4* ob = (float4*)(out + (size_t)b * OUT_CH * HW) + p4;
    ob[0]            = clamp4(a0, b0);
    ob[HW / 4]       = clamp4(a1, b1);
    ob[2 * (HW / 4)] = clamp4(a2, b2);
}

extern "C" void kernel_launch(void* const* d_in, const int* in_sizes, int n_in,
                              void* d_out, int out_size, void* d_ws, size_t ws_size,
                              hipStream_t stream) {
    const float* x    = (const float*)d_in[0];  // [32, 512, 128, 128]
    const float* w    = (const float*)d_in[1];  // [32, 512]
    const float* aw   = (const float*)d_in[2];  // [512, 512]
    const float* ab   = (const float*)d_in[3];  // [512]
    const float* wk   = (const float*)d_in[4];  // [3, 512, 1, 1]
    const float* bias = (const float*)d_in[5];  // [3]
    float* out = (float*)d_out;
    float* m   = (float*)d_ws;                  // [32, 3, 512] = 192 KiB

    // Kernel 1: styles + modulated weights (16384 waves, 4 waves/block)
    styles_kernel<<<BATCH * IN_CH / 4, 256, 0, stream>>>(w, aw, ab, wk, m);

    // Kernel 2: streaming modulated conv (512 blocks * 256 threads)
    torgb_kernel<<<BATCH * 16, 256, 0, stream>>>(x, m, bias, out);
}